// Round 1
// baseline (1603.154 us; speedup 1.0000x reference)
//
#include <hip/hip_runtime.h>
#include <hip/hip_bf16.h>
#include <stdint.h>

#define E_DIM 128
#define L_SEQ 512
#define B_SZ  128

typedef _Float16 h2 __attribute__((ext_vector_type(2)));

// ---------------- workspace layout (bytes) ----------------
constexpr size_t SZ_W12 = 512 * 128 * 4;          // 262144
constexpr size_t SZ_TQ  = 10001 * 128 * 4;        // 5120512
constexpr size_t SZ_TC  = 301 * 128 * 4;          // 154112
constexpr size_t SZ_TS  = 200 * 128 * 4;          // 102400
constexpr size_t SZ_TA  = 20002 * 128 * 4;        // 10241024
constexpr size_t SZ_K   = (size_t)B_SZ * L_SEQ * 128 * 4; // 33554432

constexpr size_t OFF_W12  = 0;
constexpr size_t OFF_W13  = OFF_W12 + SZ_W12;
constexpr size_t OFF_BV2  = OFF_W13 + SZ_W12;
constexpr size_t OFF_BV3  = OFF_BV2 + 512;
constexpr size_t OFF_TQ2  = OFF_BV3 + 512;
constexpr size_t OFF_TQ3  = OFF_TQ2 + SZ_TQ;
constexpr size_t OFF_TC2  = OFF_TQ3 + SZ_TQ;
constexpr size_t OFF_TC3  = OFF_TC2 + SZ_TC;
constexpr size_t OFF_TSD2 = OFF_TC3 + SZ_TC;
constexpr size_t OFF_TSD3 = OFF_TSD2 + SZ_TS;
constexpr size_t OFF_TSD6 = OFF_TSD3 + SZ_TS;
constexpr size_t OFF_TQD2 = OFF_TSD6 + SZ_TS;
constexpr size_t OFF_TQD3 = OFF_TQD2 + SZ_TS;
constexpr size_t OFF_TQD6 = OFF_TQD3 + SZ_TS;
constexpr size_t OFF_TA4  = OFF_TQD6 + SZ_TS;
constexpr size_t OFF_TA5  = OFF_TA4 + SZ_TA;
constexpr size_t OFF_TA6  = OFF_TA5 + SZ_TA;
constexpr size_t OFF_K    = OFF_TA6 + SZ_TA;      // total ~72.5 MB

// ---------------- helpers ----------------
__device__ __forceinline__ float fdot2f(unsigned int a, unsigned int b, float c) {
#if __has_builtin(__builtin_amdgcn_fdot2)
  return __builtin_amdgcn_fdot2(__builtin_bit_cast(h2, a), __builtin_bit_cast(h2, b), c, false);
#else
  h2 x = __builtin_bit_cast(h2, a), y = __builtin_bit_cast(h2, b);
  return c + (float)x[0] * (float)y[0] + (float)x[1] * (float)y[1];
#endif
}

__device__ __forceinline__ unsigned int packh2(float a, float b) {
  h2 v; v[0] = (_Float16)a; v[1] = (_Float16)b;
  return __builtin_bit_cast(unsigned int, v);
}

__device__ __forceinline__ float fsig(float x) {
  float t = __builtin_amdgcn_exp2f(-1.4426950408889634f * x);
  return __builtin_amdgcn_rcpf(1.0f + t);
}
__device__ __forceinline__ float ftanh(float x) {
  // tanh(x) = 1 - 2/(exp(2x)+1); saturates correctly at +/-inf
  float t = __builtin_amdgcn_exp2f(2.8853900817779268f * x);
  return 1.0f - 2.0f * __builtin_amdgcn_rcpf(t + 1.0f);
}

// ---------------- prep A: W12 = W1@W2, W13 = W1@W3, bv2/bv3 = b1@W{2,3}+b{2,3} ----------------
__global__ __launch_bounds__(128, 1) void prepA_kernel(
    const float* __restrict__ W1, const float* __restrict__ W2, const float* __restrict__ W3,
    const float* __restrict__ b1, const float* __restrict__ b2, const float* __restrict__ b3,
    char* __restrict__ ws) {
  float* W12 = (float*)(ws + OFF_W12);
  float* W13 = (float*)(ws + OFF_W13);
  float* bv2 = (float*)(ws + OFF_BV2);
  float* bv3 = (float*)(ws + OFF_BV3);
  __shared__ __align__(16) float rowb[128];
  const int j = threadIdx.x;
  const int blk = blockIdx.x;
  if (blk < 8) {
    const float* M = (blk < 4) ? W2 : W3;
    float* dst = (blk < 4) ? W12 : W13;
    const int r0 = (blk & 3) * 128;
    float Mcol[128];
#pragma unroll
    for (int t = 0; t < 128; t++) Mcol[t] = M[t * 128 + j];
    for (int r = 0; r < 128; r++) {
      const int i = r0 + r;
      rowb[j] = W1[i * 128 + j];
      __syncthreads();
      float acc = 0.0f;
      const float4* r4 = (const float4*)rowb;
#pragma unroll
      for (int t4 = 0; t4 < 32; t4++) {
        float4 v = r4[t4];
        acc += v.x * Mcol[4 * t4 + 0];
        acc += v.y * Mcol[4 * t4 + 1];
        acc += v.z * Mcol[4 * t4 + 2];
        acc += v.w * Mcol[4 * t4 + 3];
      }
      dst[i * 128 + j] = acc;
      __syncthreads();
    }
  } else {
    rowb[j] = b1[j];
    __syncthreads();
    float a2 = b2[j], a3 = b3[j];
    for (int t = 0; t < 128; t++) {
      float bb = rowb[t];
      a2 += bb * W2[t * 128 + j];
      a3 += bb * W3[t * 128 + j];
    }
    bv2[j] = a2;
    bv3[j] = a3;
  }
}

// ---------------- prep B: 13 table transforms ----------------
__global__ __launch_bounds__(128, 1) void prepB_kernel(
    const float* __restrict__ q_tab, const float* __restrict__ c_tab,
    const float* __restrict__ sd_tab, const float* __restrict__ qd_tab,
    const float* __restrict__ a_tab,
    const float* __restrict__ W4, const float* __restrict__ W5, const float* __restrict__ W6,
    const float* __restrict__ b4, const float* __restrict__ b5, const float* __restrict__ b6,
    char* __restrict__ ws) {
  const float* W12 = (const float*)(ws + OFF_W12);
  const float* W13 = (const float*)(ws + OFF_W13);
  const float* bv2 = (const float*)(ws + OFF_BV2);
  const float* bv3 = (const float*)(ws + OFF_BV3);

  const float* src = nullptr; const float* M = nullptr; const float* bias = nullptr;
  float* dst = nullptr; int rows = 0;
  switch (blockIdx.y) {
    case 0:  src = q_tab;  rows = 10001; M = W12;             bias = bv2; dst = (float*)(ws + OFF_TQ2);  break;
    case 1:  src = q_tab;  rows = 10001; M = W13;             bias = bv3; dst = (float*)(ws + OFF_TQ3);  break;
    case 2:  src = c_tab;  rows = 301;   M = W12 + 128 * 128; bias = nullptr; dst = (float*)(ws + OFF_TC2);  break;
    case 3:  src = c_tab;  rows = 301;   M = W13 + 128 * 128; bias = nullptr; dst = (float*)(ws + OFF_TC3);  break;
    case 4:  src = sd_tab; rows = 200;   M = W12 + 256 * 128; bias = nullptr; dst = (float*)(ws + OFF_TSD2); break;
    case 5:  src = sd_tab; rows = 200;   M = W13 + 256 * 128; bias = nullptr; dst = (float*)(ws + OFF_TSD3); break;
    case 6:  src = sd_tab; rows = 200;   M = W6  + 256 * 128; bias = nullptr; dst = (float*)(ws + OFF_TSD6); break;
    case 7:  src = qd_tab; rows = 200;   M = W12 + 384 * 128; bias = nullptr; dst = (float*)(ws + OFF_TQD2); break;
    case 8:  src = qd_tab; rows = 200;   M = W13 + 384 * 128; bias = nullptr; dst = (float*)(ws + OFF_TQD3); break;
    case 9:  src = qd_tab; rows = 200;   M = W6  + 384 * 128; bias = nullptr; dst = (float*)(ws + OFF_TQD6); break;
    case 10: src = a_tab;  rows = 20002; M = W4  + 128 * 128; bias = b4;  dst = (float*)(ws + OFF_TA4);  break;
    case 11: src = a_tab;  rows = 20002; M = W5  + 128 * 128; bias = b5;  dst = (float*)(ws + OFF_TA5);  break;
    default: src = a_tab;  rows = 20002; M = W6  + 128 * 128; bias = b6;  dst = (float*)(ws + OFF_TA6);  break;
  }
  const int row0 = blockIdx.x * 128;
  if (row0 >= rows) return;
  const int j = threadIdx.x;
  float Mcol[128];
#pragma unroll
  for (int t = 0; t < 128; t++) Mcol[t] = M[t * 128 + j];
  const float bj = bias ? bias[j] : 0.0f;
  __shared__ __align__(16) float rowb[128];
  const int rend = (row0 + 128 < rows) ? (row0 + 128) : rows;
  for (int r = row0; r < rend; r++) {
    rowb[j] = src[r * 128 + j];
    __syncthreads();
    float acc = bj;
    const float4* r4 = (const float4*)rowb;
#pragma unroll
    for (int t4 = 0; t4 < 32; t4++) {
      float4 v = r4[t4];
      acc += v.x * Mcol[4 * t4 + 0];
      acc += v.y * Mcol[4 * t4 + 1];
      acc += v.z * Mcol[4 * t4 + 2];
      acc += v.w * Mcol[4 * t4 + 3];
    }
    dst[r * 128 + j] = acc;
    __syncthreads();
  }
}

// ---------------- the sequential scan: 1 block per batch, lane j owns feature j ----------------
__global__ __launch_bounds__(128, 1) void scan_kernel(
    const int* __restrict__ q, const int* __restrict__ c, const int* __restrict__ sd,
    const int* __restrict__ qd, const int* __restrict__ a,
    const float* __restrict__ knowledge,
    const float* __restrict__ W2, const float* __restrict__ W3, const float* __restrict__ W4,
    const float* __restrict__ W5, const float* __restrict__ W6,
    char* __restrict__ ws) {
  const int j = threadIdx.x;
  const int b = blockIdx.x;

  const float* Tq2 = (const float*)(ws + OFF_TQ2);
  const float* Tq3 = (const float*)(ws + OFF_TQ3);
  const float* Tc2 = (const float*)(ws + OFF_TC2);
  const float* Tc3 = (const float*)(ws + OFF_TC3);
  const float* Ts2 = (const float*)(ws + OFF_TSD2);
  const float* Ts3 = (const float*)(ws + OFF_TSD3);
  const float* Ts6 = (const float*)(ws + OFF_TSD6);
  const float* Td2 = (const float*)(ws + OFF_TQD2);
  const float* Td3 = (const float*)(ws + OFF_TQD3);
  const float* Td6 = (const float*)(ws + OFF_TQD6);
  const float* Ta4 = (const float*)(ws + OFF_TA4);
  const float* Ta5 = (const float*)(ws + OFF_TA5);
  const float* Ta6 = (const float*)(ws + OFF_TA6);
  float* Kout = (float*)(ws + OFF_K);

  // weight columns in registers as f16 pairs (pair p = rows 2p,2p+1 of column j)
  unsigned int w2p[64], w3p[64], w6p[64], w4p[64], w5p[64];
#pragma unroll
  for (int p = 0; p < 64; p++) {
    w2p[p] = packh2(W2[(2 * p) * 128 + j], W2[(2 * p + 1) * 128 + j]);
    w3p[p] = packh2(W3[(2 * p) * 128 + j], W3[(2 * p + 1) * 128 + j]);
    w6p[p] = packh2(W6[(2 * p) * 128 + j], W6[(2 * p + 1) * 128 + j]);
    w4p[p] = packh2(W4[(2 * p) * 128 + j], W4[(2 * p + 1) * 128 + j]);
    w5p[p] = packh2(W5[(2 * p) * 128 + j], W5[(2 * p + 1) * 128 + j]);
  }

  __shared__ __align__(16) unsigned int kpair[64];
  __shared__ __align__(16) unsigned int sdfp[64];

  float k = knowledge[j];
  ((_Float16*)kpair)[j] = (_Float16)k;
  __syncthreads();

  const int* qb = q + b * L_SEQ;
  const int* cb = c + b * L_SEQ;
  const int* sb = sd + b * L_SEQ;
  const int* db = qd + b * L_SEQ;
  const int* ab = a + b * L_SEQ;

  // prefetch step-0 gathers
  int qi = qb[0], ci = cb[0], si = sb[0], di = db[0], ai = ab[0];
  float gq2 = Tq2[qi * 128 + j], gq3 = Tq3[qi * 128 + j];
  float gc2 = Tc2[ci * 128 + j], gc3 = Tc3[ci * 128 + j];
  float gs2 = Ts2[si * 128 + j], gs3 = Ts3[si * 128 + j], gs6 = Ts6[si * 128 + j];
  float gd2 = Td2[di * 128 + j], gd3 = Td3[di * 128 + j], gd6 = Td6[di * 128 + j];
  float ga4 = Ta4[ai * 128 + j], ga5 = Ta5[ai * 128 + j], ga6 = Ta6[ai * 128 + j];

#pragma unroll 1
  for (int l = 0; l < L_SEQ; l++) {
    const float X2 = gq2 + gc2 + gs2 + gd2;       // x@W2 + b2   (column j)
    const float X3 = gq3 + gc3 + gs3 + gd3;       // x@W3 + b3
    const float X6 = ga6 + gs6 + gd6;             // [a,sd,qd]@W6[128:512] + b6
    const float A4v = ga4, A5v = ga5;             // a@W4[128:256]+b4, a@W5[128:256]+b5

    // prefetch next step's gathers (hidden under the dot loops)
    const int ln = (l + 1 < L_SEQ) ? (l + 1) : l;
    qi = qb[ln]; ci = cb[ln]; si = sb[ln]; di = db[ln]; ai = ab[ln];
    gq2 = Tq2[qi * 128 + j]; gq3 = Tq3[qi * 128 + j];
    gc2 = Tc2[ci * 128 + j]; gc3 = Tc3[ci * 128 + j];
    gs2 = Ts2[si * 128 + j]; gs3 = Ts3[si * 128 + j]; gs6 = Ts6[si * 128 + j];
    gd2 = Td2[di * 128 + j]; gd3 = Td3[di * 128 + j]; gd6 = Td6[di * 128 + j];
    ga4 = Ta4[ai * 128 + j]; ga5 = Ta5[ai * 128 + j]; ga6 = Ta6[ai * 128 + j];

    // stage A: u2 = k@W2col, u3 = k@W3col, u6 = k@W6col  (6 chains for latency)
    float u2a = 0.f, u2b = 0.f, u3a = 0.f, u3b = 0.f, u6a = 0.f, u6b = 0.f;
    const uint4* kp4 = (const uint4*)kpair;
#pragma unroll
    for (int p = 0; p < 16; p++) {
      uint4 kv = kp4[p];
      u2a = fdot2f(kv.x, w2p[4 * p + 0], u2a);
      u3a = fdot2f(kv.x, w3p[4 * p + 0], u3a);
      u6a = fdot2f(kv.x, w6p[4 * p + 0], u6a);
      u2b = fdot2f(kv.y, w2p[4 * p + 1], u2b);
      u3b = fdot2f(kv.y, w3p[4 * p + 1], u3b);
      u6b = fdot2f(kv.y, w6p[4 * p + 1], u6b);
      u2a = fdot2f(kv.z, w2p[4 * p + 2], u2a);
      u3a = fdot2f(kv.z, w3p[4 * p + 2], u3a);
      u6a = fdot2f(kv.z, w6p[4 * p + 2], u6a);
      u2b = fdot2f(kv.w, w2p[4 * p + 3], u2b);
      u3b = fdot2f(kv.w, w3p[4 * p + 3], u3b);
      u6b = fdot2f(kv.w, w6p[4 * p + 3], u6b);
    }
    const float u2 = X2 - (u2a + u2b);   // qq@W2+b2 = x@W2+b2 - k@W2
    const float u3 = X3 - (u3a + u3b);
    const float u6 = X6 + (u6a + u6b);   // ins@W6+b6
    const float sdft = fsig(u2) * ftanh(u3);
    const float g = fsig(u6);
    ((_Float16*)sdfp)[j] = (_Float16)sdft;
    __syncthreads();

    // stage B: u4 = SDFt@W4col, u5 = SDFt@W5col
    float u4a = 0.f, u4b = 0.f, u5a = 0.f, u5b = 0.f;
    const uint4* sp4 = (const uint4*)sdfp;
#pragma unroll
    for (int p = 0; p < 16; p++) {
      uint4 sv = sp4[p];
      u4a = fdot2f(sv.x, w4p[4 * p + 0], u4a);
      u5a = fdot2f(sv.x, w5p[4 * p + 0], u5a);
      u4b = fdot2f(sv.y, w4p[4 * p + 1], u4b);
      u5b = fdot2f(sv.y, w5p[4 * p + 1], u5b);
      u4a = fdot2f(sv.z, w4p[4 * p + 2], u4a);
      u5a = fdot2f(sv.z, w5p[4 * p + 2], u5a);
      u4b = fdot2f(sv.w, w4p[4 * p + 3], u4b);
      u5b = fdot2f(sv.w, w5p[4 * p + 3], u5b);
    }
    const float pk = fsig(u4a + u4b + A4v) * ftanh(u5a + u5b + A5v);
    const float kn = g * k + (1.0f - g) * pk;

    Kout[((size_t)(b * L_SEQ + l)) * 128 + j] = kn;
    ((_Float16*)kpair)[j] = (_Float16)kn;   // safe: stage-A reads finished before barrier 1
    k = kn;
    __syncthreads();
  }
}

// ---------------- logits head: out = sigmoid(K @ Wf + bf) ----------------
__global__ __launch_bounds__(256, 4) void logits_kernel(
    const float* __restrict__ Wf, const float* __restrict__ bf,
    const char* __restrict__ ws, float* __restrict__ out) {
  const float* K = (const float*)(ws + OFF_K);
  const int t = blockIdx.x * 256 + threadIdx.x;
  if (t >= B_SZ * L_SEQ * 10) return;
  const int r = t / 10;
  const int i = t - 10 * r;
  float acc = bf[i];
  const float* kr = K + (size_t)r * 128;
#pragma unroll 8
  for (int jj = 0; jj < 128; jj++) acc += kr[jj] * Wf[jj * 10 + i];
  out[t] = fsig(acc);
}

extern "C" void kernel_launch(void* const* d_in, const int* in_sizes, int n_in,
                              void* d_out, int out_size, void* d_ws, size_t ws_size,
                              hipStream_t stream) {
  const int* q  = (const int*)d_in[0];
  const int* c  = (const int*)d_in[1];
  const int* sd = (const int*)d_in[2];
  const int* qd = (const int*)d_in[3];
  const int* a  = (const int*)d_in[4];
  const float* knowledge = (const float*)d_in[9];
  const float* q_tab  = (const float*)d_in[10];
  const float* c_tab  = (const float*)d_in[11];
  const float* sd_tab = (const float*)d_in[12];
  const float* qd_tab = (const float*)d_in[13];
  const float* a_tab  = (const float*)d_in[14];
  const float* W1 = (const float*)d_in[15];
  const float* b1 = (const float*)d_in[16];
  const float* W2 = (const float*)d_in[17];
  const float* b2 = (const float*)d_in[18];
  const float* W3 = (const float*)d_in[19];
  const float* b3 = (const float*)d_in[20];
  const float* W4 = (const float*)d_in[21];
  const float* b4 = (const float*)d_in[22];
  const float* W5 = (const float*)d_in[23];
  const float* b5 = (const float*)d_in[24];
  const float* W6 = (const float*)d_in[25];
  const float* b6 = (const float*)d_in[26];
  const float* Wf = (const float*)d_in[27];
  const float* bf = (const float*)d_in[28];
  char* ws = (char*)d_ws;
  float* out = (float*)d_out;

  prepA_kernel<<<9, 128, 0, stream>>>(W1, W2, W3, b1, b2, b3, ws);
  prepB_kernel<<<dim3(157, 13), 128, 0, stream>>>(q_tab, c_tab, sd_tab, qd_tab, a_tab,
                                                  W4, W5, W6, b4, b5, b6, ws);
  scan_kernel<<<B_SZ, 128, 0, stream>>>(q, c, sd, qd, a, knowledge, W2, W3, W4, W5, W6, ws);
  logits_kernel<<<(B_SZ * L_SEQ * 10 + 255) / 256, 256, 0, stream>>>(Wf, bf, ws, out);
}

// Round 2
// 924.459 us; speedup vs baseline: 1.7342x; 1.7342x over previous
//
#include <hip/hip_runtime.h>
#include <hip/hip_bf16.h>
#include <stdint.h>

#define E_DIM 128
#define L_SEQ 512
#define B_SZ  128

typedef _Float16 h2 __attribute__((ext_vector_type(2)));

// ---------------- workspace layout (bytes) ----------------
constexpr size_t SZ_W12 = 512 * 128 * 4;          // 262144
constexpr size_t SZ_TQ  = 10001 * 128 * 4;        // 5120512
constexpr size_t SZ_TC  = 301 * 128 * 4;          // 154112
constexpr size_t SZ_TS  = 200 * 128 * 4;          // 102400
constexpr size_t SZ_TA  = 20002 * 128 * 4;        // 10241024
constexpr size_t SZ_K   = (size_t)B_SZ * L_SEQ * 128 * 4; // 33554432

constexpr size_t OFF_W12  = 0;
constexpr size_t OFF_W13  = OFF_W12 + SZ_W12;
constexpr size_t OFF_BV2  = OFF_W13 + SZ_W12;
constexpr size_t OFF_BV3  = OFF_BV2 + 512;
constexpr size_t OFF_TQ2  = OFF_BV3 + 512;
constexpr size_t OFF_TQ3  = OFF_TQ2 + SZ_TQ;
constexpr size_t OFF_TC2  = OFF_TQ3 + SZ_TQ;
constexpr size_t OFF_TC3  = OFF_TC2 + SZ_TC;
constexpr size_t OFF_TSD2 = OFF_TC3 + SZ_TC;
constexpr size_t OFF_TSD3 = OFF_TSD2 + SZ_TS;
constexpr size_t OFF_TSD6 = OFF_TSD3 + SZ_TS;
constexpr size_t OFF_TQD2 = OFF_TSD6 + SZ_TS;
constexpr size_t OFF_TQD3 = OFF_TQD2 + SZ_TS;
constexpr size_t OFF_TQD6 = OFF_TQD3 + SZ_TS;
constexpr size_t OFF_TA4  = OFF_TQD6 + SZ_TS;
constexpr size_t OFF_TA5  = OFF_TA4 + SZ_TA;
constexpr size_t OFF_TA6  = OFF_TA5 + SZ_TA;
constexpr size_t OFF_K    = OFF_TA6 + SZ_TA;      // total ~72.5 MB

// ---------------- helpers ----------------
__device__ __forceinline__ float fdot2f(unsigned int a, unsigned int b, float c) {
#if __has_builtin(__builtin_amdgcn_fdot2)
  return __builtin_amdgcn_fdot2(__builtin_bit_cast(h2, a), __builtin_bit_cast(h2, b), c, false);
#else
  h2 x = __builtin_bit_cast(h2, a), y = __builtin_bit_cast(h2, b);
  return c + (float)x[0] * (float)y[0] + (float)x[1] * (float)y[1];
#endif
}

__device__ __forceinline__ unsigned int packh2(float a, float b) {
  h2 v; v[0] = (_Float16)a; v[1] = (_Float16)b;
  return __builtin_bit_cast(unsigned int, v);
}

__device__ __forceinline__ float fsig(float x) {
  float t = __builtin_amdgcn_exp2f(-1.4426950408889634f * x);
  return __builtin_amdgcn_rcpf(1.0f + t);
}
__device__ __forceinline__ float ftanh(float x) {
  float t = __builtin_amdgcn_exp2f(2.8853900817779268f * x);
  return 1.0f - 2.0f * __builtin_amdgcn_rcpf(t + 1.0f);
}

// raw barrier: LDS visibility only (lgkmcnt), NO vmcnt drain -> global prefetch
// loads stay in flight across the barrier (defeats __syncthreads' vmcnt(0) drain)
#define BARRIER_RAW() asm volatile("s_waitcnt lgkmcnt(0)\n\ts_barrier" ::: "memory")

// ---------------- prep A: W12 = W1@W2, W13 = W1@W3, bv2/bv3 = b1@W{2,3}+b{2,3} ----------------
__global__ __launch_bounds__(128, 1) void prepA_kernel(
    const float* __restrict__ W1, const float* __restrict__ W2, const float* __restrict__ W3,
    const float* __restrict__ b1, const float* __restrict__ b2, const float* __restrict__ b3,
    char* __restrict__ ws) {
  float* W12 = (float*)(ws + OFF_W12);
  float* W13 = (float*)(ws + OFF_W13);
  float* bv2 = (float*)(ws + OFF_BV2);
  float* bv3 = (float*)(ws + OFF_BV3);
  __shared__ __align__(16) float rowb[8][128];
  const int j = threadIdx.x;
  const int blk = blockIdx.x;
  if (blk < 8) {
    const float* M = (blk < 4) ? W2 : W3;
    float* dst = (blk < 4) ? W12 : W13;
    const int r0 = (blk & 3) * 128;
    float Mcol[128];
#pragma unroll
    for (int t = 0; t < 128; t++) Mcol[t] = M[t * 128 + j];
    for (int rb = 0; rb < 128; rb += 8) {
#pragma unroll
      for (int rr = 0; rr < 8; rr++) rowb[rr][j] = W1[(r0 + rb + rr) * 128 + j];
      __syncthreads();
#pragma unroll
      for (int rr = 0; rr < 8; rr++) {
        float acc = 0.0f;
        const float4* r4 = (const float4*)rowb[rr];
#pragma unroll
        for (int t4 = 0; t4 < 32; t4++) {
          float4 v = r4[t4];
          acc += v.x * Mcol[4 * t4 + 0];
          acc += v.y * Mcol[4 * t4 + 1];
          acc += v.z * Mcol[4 * t4 + 2];
          acc += v.w * Mcol[4 * t4 + 3];
        }
        dst[(r0 + rb + rr) * 128 + j] = acc;
      }
      __syncthreads();
    }
  } else {
    rowb[0][j] = b1[j];
    __syncthreads();
    float a2 = b2[j], a3 = b3[j];
    for (int t = 0; t < 128; t++) {
      float bb = rowb[0][t];
      a2 += bb * W2[t * 128 + j];
      a3 += bb * W3[t * 128 + j];
    }
    bv2[j] = a2;
    bv3[j] = a3;
  }
}

// ---------------- prep B: 13 table transforms (8 rows per barrier) ----------------
__global__ __launch_bounds__(128, 1) void prepB_kernel(
    const float* __restrict__ q_tab, const float* __restrict__ c_tab,
    const float* __restrict__ sd_tab, const float* __restrict__ qd_tab,
    const float* __restrict__ a_tab,
    const float* __restrict__ W4, const float* __restrict__ W5, const float* __restrict__ W6,
    const float* __restrict__ b4, const float* __restrict__ b5, const float* __restrict__ b6,
    char* __restrict__ ws) {
  const float* W12 = (const float*)(ws + OFF_W12);
  const float* W13 = (const float*)(ws + OFF_W13);
  const float* bv2 = (const float*)(ws + OFF_BV2);
  const float* bv3 = (const float*)(ws + OFF_BV3);

  const float* src = nullptr; const float* M = nullptr; const float* bias = nullptr;
  float* dst = nullptr; int rows = 0;
  switch (blockIdx.y) {
    case 0:  src = q_tab;  rows = 10001; M = W12;             bias = bv2; dst = (float*)(ws + OFF_TQ2);  break;
    case 1:  src = q_tab;  rows = 10001; M = W13;             bias = bv3; dst = (float*)(ws + OFF_TQ3);  break;
    case 2:  src = c_tab;  rows = 301;   M = W12 + 128 * 128; bias = nullptr; dst = (float*)(ws + OFF_TC2);  break;
    case 3:  src = c_tab;  rows = 301;   M = W13 + 128 * 128; bias = nullptr; dst = (float*)(ws + OFF_TC3);  break;
    case 4:  src = sd_tab; rows = 200;   M = W12 + 256 * 128; bias = nullptr; dst = (float*)(ws + OFF_TSD2); break;
    case 5:  src = sd_tab; rows = 200;   M = W13 + 256 * 128; bias = nullptr; dst = (float*)(ws + OFF_TSD3); break;
    case 6:  src = sd_tab; rows = 200;   M = W6  + 256 * 128; bias = nullptr; dst = (float*)(ws + OFF_TSD6); break;
    case 7:  src = qd_tab; rows = 200;   M = W12 + 384 * 128; bias = nullptr; dst = (float*)(ws + OFF_TQD2); break;
    case 8:  src = qd_tab; rows = 200;   M = W13 + 384 * 128; bias = nullptr; dst = (float*)(ws + OFF_TQD3); break;
    case 9:  src = qd_tab; rows = 200;   M = W6  + 384 * 128; bias = nullptr; dst = (float*)(ws + OFF_TQD6); break;
    case 10: src = a_tab;  rows = 20002; M = W4  + 128 * 128; bias = b4;  dst = (float*)(ws + OFF_TA4);  break;
    case 11: src = a_tab;  rows = 20002; M = W5  + 128 * 128; bias = b5;  dst = (float*)(ws + OFF_TA5);  break;
    default: src = a_tab;  rows = 20002; M = W6  + 128 * 128; bias = b6;  dst = (float*)(ws + OFF_TA6);  break;
  }
  const int row0 = blockIdx.x * 128;
  if (row0 >= rows) return;
  const int j = threadIdx.x;
  float Mcol[128];
#pragma unroll
  for (int t = 0; t < 128; t++) Mcol[t] = M[t * 128 + j];
  const float bj = bias ? bias[j] : 0.0f;
  __shared__ __align__(16) float rowb[8][128];
  const int rend = (row0 + 128 < rows) ? (row0 + 128) : rows;
  for (int rb = row0; rb < rend; rb += 8) {
    const int nr = (rb + 8 <= rend) ? 8 : (rend - rb);
#pragma unroll
    for (int rr = 0; rr < 8; rr++)
      rowb[rr][j] = src[(rb + (rr < nr ? rr : 0)) * 128 + j];
    __syncthreads();
#pragma unroll
    for (int rr = 0; rr < 8; rr++) {
      if (rr < nr) {
        float acc = bj;
        const float4* r4 = (const float4*)rowb[rr];
#pragma unroll
        for (int t4 = 0; t4 < 32; t4++) {
          float4 v = r4[t4];
          acc += v.x * Mcol[4 * t4 + 0];
          acc += v.y * Mcol[4 * t4 + 1];
          acc += v.z * Mcol[4 * t4 + 2];
          acc += v.w * Mcol[4 * t4 + 3];
        }
        dst[(rb + rr) * 128 + j] = acc;
      }
    }
    __syncthreads();
  }
}

// ---------------- scan: 1 block/batch, 256 thr = split-K halves, raw barriers ----------------
// thread (h, j): h = K-half (t in [64h,64h+64)), j = output feature.
// Weight cols held as f16 pairs: 5 mats x 32 regs = 160 VGPR (no spill).
// Gathers prefetched 2 steps ahead (named sets A/B, unroll-2 ring).

#define PREFETCH(S, P) do {                                                   \
    int _s = (S);                                                             \
    int _qi = idxb[0][_s], _ci = idxb[1][_s], _si = idxb[2][_s];              \
    int _di = idxb[3][_s], _ai = idxb[4][_s];                                 \
    P##q2 = Tq2[_qi * 128 + j]; P##q3 = Tq3[_qi * 128 + j];                   \
    P##c2 = Tc2[_ci * 128 + j]; P##c3 = Tc3[_ci * 128 + j];                   \
    P##s2 = Ts2[_si * 128 + j]; P##s3 = Ts3[_si * 128 + j];                   \
    P##s6 = Ts6[_si * 128 + j];                                               \
    P##d2 = Td2[_di * 128 + j]; P##d3 = Td3[_di * 128 + j];                   \
    P##d6 = Td6[_di * 128 + j];                                               \
    P##a4 = Ta4[_ai * 128 + j]; P##a5 = Ta5[_ai * 128 + j];                   \
    P##a6 = Ta6[_ai * 128 + j];                                               \
  } while (0)

#define SCAN_STEP(P, S2, L) do {                                              \
    /* stage A: half-dots k@W2,W3,W6 */                                       \
    float u2a = 0.f, u2b = 0.f, u3a = 0.f, u3b = 0.f, u6a = 0.f, u6b = 0.f;   \
    {                                                                         \
      const uint4* kp4 = ((const uint4*)kpair) + 8 * h;                       \
      _Pragma("unroll")                                                       \
      for (int i = 0; i < 8; i++) {                                           \
        uint4 kv = kp4[i];                                                    \
        u2a = fdot2f(kv.x, w2h[4 * i + 0], u2a);                              \
        u3a = fdot2f(kv.x, w3h[4 * i + 0], u3a);                              \
        u6a = fdot2f(kv.x, w6h[4 * i + 0], u6a);                              \
        u2b = fdot2f(kv.y, w2h[4 * i + 1], u2b);                              \
        u3b = fdot2f(kv.y, w3h[4 * i + 1], u3b);                              \
        u6b = fdot2f(kv.y, w6h[4 * i + 1], u6b);                              \
        u2a = fdot2f(kv.z, w2h[4 * i + 2], u2a);                              \
        u3a = fdot2f(kv.z, w3h[4 * i + 2], u3a);                              \
        u6a = fdot2f(kv.z, w6h[4 * i + 2], u6a);                              \
        u2b = fdot2f(kv.w, w2h[4 * i + 3], u2b);                              \
        u3b = fdot2f(kv.w, w3h[4 * i + 3], u3b);                              \
        u6b = fdot2f(kv.w, w6h[4 * i + 3], u6b);                              \
      }                                                                       \
    }                                                                         \
    pA[0][tid] = u2a + u2b; pA[1][tid] = u3a + u3b; pA[2][tid] = u6a + u6b;   \
    BARRIER_RAW(); /* B1 */                                                   \
    float o2 = pA[0][tid ^ 128], o3 = pA[1][tid ^ 128], o6 = pA[2][tid ^ 128];\
    float U2 = (P##q2 + P##c2 + P##s2 + P##d2) - (u2a + u2b + o2);            \
    float U3 = (P##q3 + P##c3 + P##s3 + P##d3) - (u3a + u3b + o3);            \
    float U6 = (P##a6 + P##s6 + P##d6) + (u6a + u6b + o6);                    \
    float sdft = fsig(U2) * ftanh(U3);                                        \
    float g = fsig(U6);                                                       \
    if (!h) ((_Float16*)sdfp)[j] = (_Float16)sdft;                            \
    BARRIER_RAW(); /* B2 */                                                   \
    /* stage B: half-dots SDFt@W4,W5 */                                       \
    float u4a = 0.f, u4b = 0.f, u5a = 0.f, u5b = 0.f;                         \
    {                                                                         \
      const uint4* sp4 = ((const uint4*)sdfp) + 8 * h;                        \
      _Pragma("unroll")                                                       \
      for (int i = 0; i < 8; i++) {                                           \
        uint4 sv = sp4[i];                                                    \
        u4a = fdot2f(sv.x, w4h[4 * i + 0], u4a);                              \
        u5a = fdot2f(sv.x, w5h[4 * i + 0], u5a);                              \
        u4b = fdot2f(sv.y, w4h[4 * i + 1], u4b);                              \
        u5b = fdot2f(sv.y, w5h[4 * i + 1], u5b);                              \
        u4a = fdot2f(sv.z, w4h[4 * i + 2], u4a);                              \
        u5a = fdot2f(sv.z, w5h[4 * i + 2], u5a);                              \
        u4b = fdot2f(sv.w, w4h[4 * i + 3], u4b);                              \
        u5b = fdot2f(sv.w, w5h[4 * i + 3], u5b);                              \
      }                                                                       \
    }                                                                         \
    pB[0][tid] = u4a + u4b; pB[1][tid] = u5a + u5b;                           \
    BARRIER_RAW(); /* B3 */                                                   \
    float o4 = pB[0][tid ^ 128], o5 = pB[1][tid ^ 128];                       \
    float pk = fsig(u4a + u4b + o4 + P##a4) * ftanh(u5a + u5b + o5 + P##a5);  \
    k = g * k + (1.0f - g) * pk;                                              \
    if (h) ((_Float16*)kpair)[j] = (_Float16)k;                               \
    BARRIER_RAW(); /* B4 */                                                   \
    if (!h) Kout[((size_t)(base + (L))) * 128 + j] = k;                       \
    PREFETCH(S2, P);                                                          \
  } while (0)

__global__ __launch_bounds__(256, 1) void scan_kernel(
    const int* __restrict__ q, const int* __restrict__ c, const int* __restrict__ sd,
    const int* __restrict__ qd, const int* __restrict__ a,
    const float* __restrict__ knowledge,
    const float* __restrict__ W2, const float* __restrict__ W3, const float* __restrict__ W4,
    const float* __restrict__ W5, const float* __restrict__ W6,
    char* __restrict__ ws) {
  const int tid = threadIdx.x;
  const int j = tid & 127;
  const int h = tid >> 7;      // K-half (wave-uniform)
  const int b = blockIdx.x;
  const int base = b * L_SEQ;

  const float* Tq2 = (const float*)(ws + OFF_TQ2);
  const float* Tq3 = (const float*)(ws + OFF_TQ3);
  const float* Tc2 = (const float*)(ws + OFF_TC2);
  const float* Tc3 = (const float*)(ws + OFF_TC3);
  const float* Ts2 = (const float*)(ws + OFF_TSD2);
  const float* Ts3 = (const float*)(ws + OFF_TSD3);
  const float* Ts6 = (const float*)(ws + OFF_TSD6);
  const float* Td2 = (const float*)(ws + OFF_TQD2);
  const float* Td3 = (const float*)(ws + OFF_TQD3);
  const float* Td6 = (const float*)(ws + OFF_TQD6);
  const float* Ta4 = (const float*)(ws + OFF_TA4);
  const float* Ta5 = (const float*)(ws + OFF_TA5);
  const float* Ta6 = (const float*)(ws + OFF_TA6);
  float* Kout = (float*)(ws + OFF_K);

  __shared__ int idxb[5][L_SEQ];                    // 10 KB, read-only after init
  __shared__ __align__(16) unsigned int kpair[64];  // k as f16 pairs
  __shared__ __align__(16) unsigned int sdfp[64];   // SDFt as f16 pairs
  __shared__ float pA[3][256];                      // stage-A partials
  __shared__ float pB[2][256];                      // stage-B partials

  // preload indices (each thread: positions tid and tid+256 of each array)
  idxb[0][tid] = q[base + tid];  idxb[0][tid + 256] = q[base + tid + 256];
  idxb[1][tid] = c[base + tid];  idxb[1][tid + 256] = c[base + tid + 256];
  idxb[2][tid] = sd[base + tid]; idxb[2][tid + 256] = sd[base + tid + 256];
  idxb[3][tid] = qd[base + tid]; idxb[3][tid + 256] = qd[base + tid + 256];
  idxb[4][tid] = a[base + tid];  idxb[4][tid + 256] = a[base + tid + 256];

  // weight half-columns as f16 pairs: 32 regs per matrix
  unsigned int w2h[32], w3h[32], w6h[32], w4h[32], w5h[32];
  const int t0 = h * 64;
#pragma unroll
  for (int p = 0; p < 32; p++) {
    w2h[p] = packh2(W2[(t0 + 2 * p) * 128 + j], W2[(t0 + 2 * p + 1) * 128 + j]);
    w3h[p] = packh2(W3[(t0 + 2 * p) * 128 + j], W3[(t0 + 2 * p + 1) * 128 + j]);
    w6h[p] = packh2(W6[(t0 + 2 * p) * 128 + j], W6[(t0 + 2 * p + 1) * 128 + j]);
    w4h[p] = packh2(W4[(t0 + 2 * p) * 128 + j], W4[(t0 + 2 * p + 1) * 128 + j]);
    w5h[p] = packh2(W5[(t0 + 2 * p) * 128 + j], W5[(t0 + 2 * p + 1) * 128 + j]);
  }

  float k = knowledge[j];
  if (h) ((_Float16*)kpair)[j] = (_Float16)k;
  __syncthreads();   // one full barrier at init is fine

  // prefetch ring: set A = step 0, set B = step 1
  float gAq2, gAq3, gAc2, gAc3, gAs2, gAs3, gAs6, gAd2, gAd3, gAd6, gAa4, gAa5, gAa6;
  float gBq2, gBq3, gBc2, gBc3, gBs2, gBs3, gBs6, gBd2, gBd3, gBd6, gBa4, gBa5, gBa6;
  PREFETCH(0, gA);
  PREFETCH(1, gB);

#pragma unroll 1
  for (int m = 0; m < L_SEQ / 2; m++) {
    const int l0 = 2 * m;
    const int s2 = (l0 + 2 < L_SEQ) ? (l0 + 2) : (L_SEQ - 1);
    const int s3 = (l0 + 3 < L_SEQ) ? (l0 + 3) : (L_SEQ - 1);
    SCAN_STEP(gA, s2, l0);
    SCAN_STEP(gB, s3, l0 + 1);
  }
}

// ---------------- logits head: out = sigmoid(K @ Wf + bf) ----------------
__global__ __launch_bounds__(256, 4) void logits_kernel(
    const float* __restrict__ Wf, const float* __restrict__ bf,
    const char* __restrict__ ws, float* __restrict__ out) {
  const float* K = (const float*)(ws + OFF_K);
  const int t = blockIdx.x * 256 + threadIdx.x;
  if (t >= B_SZ * L_SEQ * 10) return;
  const int r = t / 10;
  const int i = t - 10 * r;
  float acc = bf[i];
  const float* kr = K + (size_t)r * 128;
#pragma unroll 8
  for (int jj = 0; jj < 128; jj++) acc += kr[jj] * Wf[jj * 10 + i];
  out[t] = fsig(acc);
}

extern "C" void kernel_launch(void* const* d_in, const int* in_sizes, int n_in,
                              void* d_out, int out_size, void* d_ws, size_t ws_size,
                              hipStream_t stream) {
  const int* q  = (const int*)d_in[0];
  const int* c  = (const int*)d_in[1];
  const int* sd = (const int*)d_in[2];
  const int* qd = (const int*)d_in[3];
  const int* a  = (const int*)d_in[4];
  const float* knowledge = (const float*)d_in[9];
  const float* q_tab  = (const float*)d_in[10];
  const float* c_tab  = (const float*)d_in[11];
  const float* sd_tab = (const float*)d_in[12];
  const float* qd_tab = (const float*)d_in[13];
  const float* a_tab  = (const float*)d_in[14];
  const float* W1 = (const float*)d_in[15];
  const float* b1 = (const float*)d_in[16];
  const float* W2 = (const float*)d_in[17];
  const float* b2 = (const float*)d_in[18];
  const float* W3 = (const float*)d_in[19];
  const float* b3 = (const float*)d_in[20];
  const float* W4 = (const float*)d_in[21];
  const float* b4 = (const float*)d_in[22];
  const float* W5 = (const float*)d_in[23];
  const float* b5 = (const float*)d_in[24];
  const float* W6 = (const float*)d_in[25];
  const float* b6 = (const float*)d_in[26];
  const float* Wf = (const float*)d_in[27];
  const float* bf = (const float*)d_in[28];
  char* ws = (char*)d_ws;
  float* out = (float*)d_out;

  prepA_kernel<<<9, 128, 0, stream>>>(W1, W2, W3, b1, b2, b3, ws);
  prepB_kernel<<<dim3(157, 13), 128, 0, stream>>>(q_tab, c_tab, sd_tab, qd_tab, a_tab,
                                                  W4, W5, W6, b4, b5, b6, ws);
  scan_kernel<<<B_SZ, 256, 0, stream>>>(q, c, sd, qd, a, knowledge, W2, W3, W4, W5, W6, ws);
  logits_kernel<<<(B_SZ * L_SEQ * 10 + 255) / 256, 256, 0, stream>>>(Wf, bf, ws, out);
}

// Round 3
// 793.758 us; speedup vs baseline: 2.0197x; 1.1647x over previous
//
#include <hip/hip_runtime.h>
#include <hip/hip_bf16.h>
#include <stdint.h>

#define E_DIM 128
#define L_SEQ 512
#define B_SZ  128

typedef _Float16 h2 __attribute__((ext_vector_type(2)));
typedef _Float16 f16x8 __attribute__((ext_vector_type(8)));
typedef float f32x4 __attribute__((ext_vector_type(4)));

// ---------------- workspace layout (bytes) ----------------
constexpr size_t SZ_W12 = 512 * 128 * 4;
constexpr size_t SZ_TQ  = 10001 * 128 * 4;
constexpr size_t SZ_TC  = 301 * 128 * 4;
constexpr size_t SZ_TS  = 200 * 128 * 4;
constexpr size_t SZ_TA  = 20002 * 128 * 4;

constexpr size_t OFF_W12  = 0;
constexpr size_t OFF_W13  = OFF_W12 + SZ_W12;
constexpr size_t OFF_BV2  = OFF_W13 + SZ_W12;
constexpr size_t OFF_BV3  = OFF_BV2 + 512;
constexpr size_t OFF_TQ2  = OFF_BV3 + 512;
constexpr size_t OFF_TQ3  = OFF_TQ2 + SZ_TQ;
constexpr size_t OFF_TC2  = OFF_TQ3 + SZ_TQ;
constexpr size_t OFF_TC3  = OFF_TC2 + SZ_TC;
constexpr size_t OFF_TSD2 = OFF_TC3 + SZ_TC;
constexpr size_t OFF_TSD3 = OFF_TSD2 + SZ_TS;
constexpr size_t OFF_TSD6 = OFF_TSD3 + SZ_TS;
constexpr size_t OFF_TQD2 = OFF_TSD6 + SZ_TS;
constexpr size_t OFF_TQD3 = OFF_TQD2 + SZ_TS;
constexpr size_t OFF_TQD6 = OFF_TQD3 + SZ_TS;
constexpr size_t OFF_TA4  = OFF_TQD6 + SZ_TS;
constexpr size_t OFF_TA5  = OFF_TA4 + SZ_TA;
constexpr size_t OFF_TA6  = OFF_TA5 + SZ_TA;
constexpr size_t OFF_K    = OFF_TA6 + SZ_TA;      // 128*512*128*4 = 33.5 MB

// ---------------- helpers ----------------
__device__ __forceinline__ float fdot2f(unsigned int a, unsigned int b, float c) {
#if __has_builtin(__builtin_amdgcn_fdot2)
  return __builtin_amdgcn_fdot2(__builtin_bit_cast(h2, a), __builtin_bit_cast(h2, b), c, false);
#else
  h2 x = __builtin_bit_cast(h2, a), y = __builtin_bit_cast(h2, b);
  return c + (float)x[0] * (float)y[0] + (float)x[1] * (float)y[1];
#endif
}

__device__ __forceinline__ unsigned int packh2(float a, float b) {
  h2 v; v[0] = (_Float16)a; v[1] = (_Float16)b;
  return __builtin_bit_cast(unsigned int, v);
}

__device__ __forceinline__ float fsig(float x) {
  float t = __builtin_amdgcn_exp2f(-1.4426950408889634f * x);
  return __builtin_amdgcn_rcpf(1.0f + t);
}
__device__ __forceinline__ float ftanh(float x) {
  float t = __builtin_amdgcn_exp2f(2.8853900817779268f * x);
  return 1.0f - 2.0f * __builtin_amdgcn_rcpf(t + 1.0f);
}

// LDS-only barrier: no vmcnt drain -> global prefetch stays in flight
#define BARRIER_RAW() asm volatile("s_waitcnt lgkmcnt(0)\n\ts_barrier" ::: "memory")

// ---------------- prep A: W12 = W1@W2, W13 = W1@W3, bv2/bv3 = b1@W{2,3}+b{2,3} ----------------
__global__ __launch_bounds__(128, 1) void prepA_kernel(
    const float* __restrict__ W1, const float* __restrict__ W2, const float* __restrict__ W3,
    const float* __restrict__ b1, const float* __restrict__ b2, const float* __restrict__ b3,
    char* __restrict__ ws) {
  float* W12 = (float*)(ws + OFF_W12);
  float* W13 = (float*)(ws + OFF_W13);
  float* bv2 = (float*)(ws + OFF_BV2);
  float* bv3 = (float*)(ws + OFF_BV3);
  __shared__ __align__(16) float rowb[8][128];
  const int j = threadIdx.x;
  const int blk = blockIdx.x;
  if (blk < 8) {
    const float* M = (blk < 4) ? W2 : W3;
    float* dst = (blk < 4) ? W12 : W13;
    const int r0 = (blk & 3) * 128;
    float Mcol[128];
#pragma unroll
    for (int t = 0; t < 128; t++) Mcol[t] = M[t * 128 + j];
    for (int rb = 0; rb < 128; rb += 8) {
#pragma unroll
      for (int rr = 0; rr < 8; rr++) rowb[rr][j] = W1[(r0 + rb + rr) * 128 + j];
      __syncthreads();
#pragma unroll
      for (int rr = 0; rr < 8; rr++) {
        float acc = 0.0f;
        const float4* r4 = (const float4*)rowb[rr];
#pragma unroll
        for (int t4 = 0; t4 < 32; t4++) {
          float4 v = r4[t4];
          acc += v.x * Mcol[4 * t4 + 0];
          acc += v.y * Mcol[4 * t4 + 1];
          acc += v.z * Mcol[4 * t4 + 2];
          acc += v.w * Mcol[4 * t4 + 3];
        }
        dst[(r0 + rb + rr) * 128 + j] = acc;
      }
      __syncthreads();
    }
  } else {
    rowb[0][j] = b1[j];
    __syncthreads();
    float a2 = b2[j], a3 = b3[j];
    for (int t = 0; t < 128; t++) {
      float bb = rowb[0][t];
      a2 += bb * W2[t * 128 + j];
      a3 += bb * W3[t * 128 + j];
    }
    bv2[j] = a2;
    bv3[j] = a3;
  }
}

// ---------------- table-transform GEMM via MFMA (f16 in, f32 out) ----------------
// C[rows x (NSEG*128)] = A[rows x 128] @ B[128 x NSEG*128] (+bias), outputs split
// per 128-col segment into separate dst arrays.
// mfma_f32_16x16x32_f16 layouts: A lane l: row=l&15, k=(l>>4)*8+e (contig 8);
// B lane l: col=l&15, k=(l>>4)*8+e; C/D lane l: col=l&15, row=(l>>4)*4+reg.
template <int NSEG>
__global__ __launch_bounds__(256, 1) void gemm_tabs_kernel(
    const float* __restrict__ q_tab, const float* __restrict__ c_tab,
    const float* __restrict__ sd_tab, const float* __restrict__ qd_tab,
    const float* __restrict__ a_tab,
    const float* __restrict__ W4, const float* __restrict__ W5, const float* __restrict__ W6,
    const float* __restrict__ b4, const float* __restrict__ b5, const float* __restrict__ b6,
    char* __restrict__ ws) {
  constexpr int WD  = NSEG * 128;   // B width
  constexpr int SPAN = WD / 4;      // cols per wave
  constexpr int NCT = SPAN / 16;    // 16-col tiles per wave

  __shared__ _Float16 BT[WD][136];          // B transposed [col][k], padded
  __shared__ _Float16 At[32][136];          // A chunk [row][k], padded
  __shared__ float biasL[384];

  const float* W12 = (const float*)(ws + OFF_W12);
  const float* W13 = (const float*)(ws + OFF_W13);
  const float* bv2 = (const float*)(ws + OFF_BV2);
  const float* bv3 = (const float*)(ws + OFF_BV3);

  const int bid = blockIdx.x;
  const int tid = threadIdx.x;
  const int wv = tid >> 6, ln = tid & 63;

  // block -> (table, row block)
  const float* src; int rows; int blk_in;
  const float* bsrc[3]; int koff[3]; const float* bias[3]; float* dst[3];
  if (NSEG == 2) {
    if (bid < 79) { src = q_tab; rows = 10001; blk_in = bid;
      bsrc[0] = W12; bsrc[1] = W13; koff[0] = koff[1] = 0;
      bias[0] = bv2; bias[1] = bv3;
      dst[0] = (float*)(ws + OFF_TQ2); dst[1] = (float*)(ws + OFF_TQ3);
    } else { src = c_tab; rows = 301; blk_in = bid - 79;
      bsrc[0] = W12; bsrc[1] = W13; koff[0] = koff[1] = 128;
      bias[0] = bias[1] = nullptr;
      dst[0] = (float*)(ws + OFF_TC2); dst[1] = (float*)(ws + OFF_TC3);
    }
    bsrc[2] = nullptr; koff[2] = 0; bias[2] = nullptr; dst[2] = nullptr;
  } else {
    if (bid < 2) { src = sd_tab; rows = 200; blk_in = bid;
      bsrc[0] = W12; bsrc[1] = W13; bsrc[2] = W6; koff[0] = koff[1] = koff[2] = 256;
      bias[0] = bias[1] = bias[2] = nullptr;
      dst[0] = (float*)(ws + OFF_TSD2); dst[1] = (float*)(ws + OFF_TSD3); dst[2] = (float*)(ws + OFF_TSD6);
    } else if (bid < 4) { src = qd_tab; rows = 200; blk_in = bid - 2;
      bsrc[0] = W12; bsrc[1] = W13; bsrc[2] = W6; koff[0] = koff[1] = koff[2] = 384;
      bias[0] = bias[1] = bias[2] = nullptr;
      dst[0] = (float*)(ws + OFF_TQD2); dst[1] = (float*)(ws + OFF_TQD3); dst[2] = (float*)(ws + OFF_TQD6);
    } else { src = a_tab; rows = 20002; blk_in = bid - 4;
      bsrc[0] = W4; bsrc[1] = W5; bsrc[2] = W6; koff[0] = koff[1] = koff[2] = 128;
      bias[0] = b4; bias[1] = b5; bias[2] = b6;
      dst[0] = (float*)(ws + OFF_TA4); dst[1] = (float*)(ws + OFF_TA5); dst[2] = (float*)(ws + OFF_TA6);
    }
  }

  // ---- stage B into LDS (transposed, f16) + bias ----
#pragma unroll
  for (int s = 0; s < NSEG; s++) {
    const float* M = bsrc[s] + (size_t)koff[s] * 128;
    const int jj = tid & 127, kb = tid >> 7;
    for (int k0 = 0; k0 < 128; k0 += 2) {
      const int k = k0 + kb;
      BT[s * 128 + jj][k] = (_Float16)M[k * 128 + jj];
    }
    if (tid < 128) biasL[s * 128 + tid] = bias[s] ? bias[s][tid] : 0.0f;
  }
  __syncthreads();

  // ---- hoist B fragments to VGPRs ----
  f16x8 bf[NCT][4];
#pragma unroll
  for (int ct = 0; ct < NCT; ct++)
#pragma unroll
    for (int kt = 0; kt < 4; kt++) {
      const int col = wv * SPAN + ct * 16 + (ln & 15);
      const int k = kt * 32 + (ln >> 4) * 8;
      bf[ct][kt] = *(const f16x8*)&BT[col][k];
    }
  float bvl[NCT];
#pragma unroll
  for (int ct = 0; ct < NCT; ct++) bvl[ct] = biasL[wv * SPAN + ct * 16 + (ln & 15)];

  // ---- loop over 4 chunks of 32 rows ----
  const int row_base = blk_in * 128;
  for (int ch = 0; ch < 4; ch++) {
    const int row0 = row_base + ch * 32;
    // stage A chunk (f32 -> f16)
    {
      const int r = tid >> 3, cb = (tid & 7) * 16;
      int sr = row0 + r; if (sr >= rows) sr = rows - 1;
      const float4* s4 = (const float4*)(src + (size_t)sr * 128 + cb);
      float4 v0 = s4[0], v1 = s4[1], v2 = s4[2], v3 = s4[3];
      f16x8 lo, hi;
      lo[0] = (_Float16)v0.x; lo[1] = (_Float16)v0.y; lo[2] = (_Float16)v0.z; lo[3] = (_Float16)v0.w;
      lo[4] = (_Float16)v1.x; lo[5] = (_Float16)v1.y; lo[6] = (_Float16)v1.z; lo[7] = (_Float16)v1.w;
      hi[0] = (_Float16)v2.x; hi[1] = (_Float16)v2.y; hi[2] = (_Float16)v2.z; hi[3] = (_Float16)v2.w;
      hi[4] = (_Float16)v3.x; hi[5] = (_Float16)v3.y; hi[6] = (_Float16)v3.z; hi[7] = (_Float16)v3.w;
      *(f16x8*)&At[r][cb] = lo;
      *(f16x8*)&At[r][cb + 8] = hi;
    }
    __syncthreads();
    // A fragments
    f16x8 af[2][4];
#pragma unroll
    for (int rt = 0; rt < 2; rt++)
#pragma unroll
      for (int kt = 0; kt < 4; kt++) {
        const int row = rt * 16 + (ln & 15);
        const int k = kt * 32 + (ln >> 4) * 8;
        af[rt][kt] = *(const f16x8*)&At[row][k];
      }
    // MFMA accumulate
    f32x4 acc[2][NCT];
#pragma unroll
    for (int rt = 0; rt < 2; rt++)
#pragma unroll
      for (int ct = 0; ct < NCT; ct++) acc[rt][ct] = (f32x4){0.f, 0.f, 0.f, 0.f};
#pragma unroll
    for (int kt = 0; kt < 4; kt++)
#pragma unroll
      for (int ct = 0; ct < NCT; ct++)
#pragma unroll
        for (int rt = 0; rt < 2; rt++)
          acc[rt][ct] = __builtin_amdgcn_mfma_f32_16x16x32_f16(af[rt][kt], bf[ct][kt], acc[rt][ct], 0, 0, 0);
    // epilogue
#pragma unroll
    for (int ct = 0; ct < NCT; ct++) {
      const int gcol = wv * SPAN + ct * 16 + (ln & 15);
      const int seg = gcol >> 7, col = gcol & 127;
      float* D = dst[seg];
      const float bv = bvl[ct];
#pragma unroll
      for (int rt = 0; rt < 2; rt++)
#pragma unroll
        for (int e = 0; e < 4; e++) {
          const int row = row0 + rt * 16 + (ln >> 4) * 4 + e;
          if (row < rows) D[(size_t)row * 128 + col] = acc[rt][ct][e] + bv;
        }
    }
    __syncthreads();
  }
}

// ---------------- scan: 1 block/batch, split-K INSIDE the wave ----------------
// lane l of wave w: j = 32w + (l&31), h = l>>5; half-combine via shfl_xor(32);
// only 2 LDS broadcasts (sdft, k) and 2 raw barriers per step.

#define PREFETCH(S, P) do {                                                   \
    int _s = (S);                                                             \
    int _qi = idxb[0][_s], _ci = idxb[1][_s], _si = idxb[2][_s];              \
    int _di = idxb[3][_s], _ai = idxb[4][_s];                                 \
    P##q2 = Tq2[_qi * 128 + j]; P##q3 = Tq3[_qi * 128 + j];                   \
    P##c2 = Tc2[_ci * 128 + j]; P##c3 = Tc3[_ci * 128 + j];                   \
    P##s2 = Ts2[_si * 128 + j]; P##s3 = Ts3[_si * 128 + j];                   \
    P##s6 = Ts6[_si * 128 + j];                                               \
    P##d2 = Td2[_di * 128 + j]; P##d3 = Td3[_di * 128 + j];                   \
    P##d6 = Td6[_di * 128 + j];                                               \
    P##a4 = Ta4[_ai * 128 + j]; P##a5 = Ta5[_ai * 128 + j];                   \
    P##a6 = Ta6[_ai * 128 + j];                                               \
  } while (0)

#define SCAN_STEP(P, S2, L) do {                                              \
    float u2a = 0.f, u2b = 0.f, u3a = 0.f, u3b = 0.f, u6a = 0.f, u6b = 0.f;   \
    {                                                                         \
      const uint4* kp4 = ((const uint4*)kpair) + 8 * h;                       \
      _Pragma("unroll")                                                       \
      for (int i = 0; i < 8; i++) {                                           \
        uint4 kv = kp4[i];                                                    \
        u2a = fdot2f(kv.x, w2h[4 * i + 0], u2a);                              \
        u3a = fdot2f(kv.x, w3h[4 * i + 0], u3a);                              \
        u6a = fdot2f(kv.x, w6h[4 * i + 0], u6a);                              \
        u2b = fdot2f(kv.y, w2h[4 * i + 1], u2b);                              \
        u3b = fdot2f(kv.y, w3h[4 * i + 1], u3b);                              \
        u6b = fdot2f(kv.y, w6h[4 * i + 1], u6b);                              \
        u2a = fdot2f(kv.z, w2h[4 * i + 2], u2a);                              \
        u3a = fdot2f(kv.z, w3h[4 * i + 2], u3a);                              \
        u6a = fdot2f(kv.z, w6h[4 * i + 2], u6a);                              \
        u2b = fdot2f(kv.w, w2h[4 * i + 3], u2b);                              \
        u3b = fdot2f(kv.w, w3h[4 * i + 3], u3b);                              \
        u6b = fdot2f(kv.w, w6h[4 * i + 3], u6b);                              \
      }                                                                       \
    }                                                                         \
    float U2p = u2a + u2b, U3p = u3a + u3b, U6p = u6a + u6b;                  \
    U2p += __shfl_xor(U2p, 32);                                               \
    U3p += __shfl_xor(U3p, 32);                                               \
    U6p += __shfl_xor(U6p, 32);                                               \
    float U2 = (P##q2 + P##c2 + P##s2 + P##d2) - U2p;                         \
    float U3 = (P##q3 + P##c3 + P##s3 + P##d3) - U3p;                         \
    float U6 = (P##a6 + P##s6 + P##d6) + U6p;                                 \
    float sdft = fsig(U2) * ftanh(U3);                                        \
    float g = fsig(U6);                                                       \
    if (!h) ((_Float16*)sdfp)[j] = (_Float16)sdft;                            \
    BARRIER_RAW(); /* B1: sdft broadcast */                                   \
    float u4a = 0.f, u4b = 0.f, u5a = 0.f, u5b = 0.f;                         \
    {                                                                         \
      const uint4* sp4 = ((const uint4*)sdfp) + 8 * h;                        \
      _Pragma("unroll")                                                       \
      for (int i = 0; i < 8; i++) {                                           \
        uint4 sv = sp4[i];                                                    \
        u4a = fdot2f(sv.x, w4h[4 * i + 0], u4a);                              \
        u5a = fdot2f(sv.x, w5h[4 * i + 0], u5a);                              \
        u4b = fdot2f(sv.y, w4h[4 * i + 1], u4b);                              \
        u5b = fdot2f(sv.y, w5h[4 * i + 1], u5b);                              \
        u4a = fdot2f(sv.z, w4h[4 * i + 2], u4a);                              \
        u5a = fdot2f(sv.z, w5h[4 * i + 2], u5a);                              \
        u4b = fdot2f(sv.w, w4h[4 * i + 3], u4b);                              \
        u5b = fdot2f(sv.w, w5h[4 * i + 3], u5b);                              \
      }                                                                       \
    }                                                                         \
    float U4p = u4a + u4b, U5p = u5a + u5b;                                   \
    U4p += __shfl_xor(U4p, 32);                                               \
    U5p += __shfl_xor(U5p, 32);                                               \
    float pk = fsig(U4p + P##a4) * ftanh(U5p + P##a5);                        \
    k = g * k + (1.0f - g) * pk;                                              \
    if (h) ((_Float16*)kpair)[j] = (_Float16)k;                               \
    if (!h) Kout[((size_t)(base + (L))) * 128 + j] = k;                       \
    PREFETCH(S2, P);                                                          \
    BARRIER_RAW(); /* B2: k broadcast */                                      \
  } while (0)

__global__ __launch_bounds__(256, 1) void scan_kernel(
    const int* __restrict__ q, const int* __restrict__ c, const int* __restrict__ sd,
    const int* __restrict__ qd, const int* __restrict__ a,
    const float* __restrict__ knowledge,
    const float* __restrict__ W2, const float* __restrict__ W3, const float* __restrict__ W4,
    const float* __restrict__ W5, const float* __restrict__ W6,
    char* __restrict__ ws) {
  const int tid = threadIdx.x;
  const int wv = tid >> 6, ln = tid & 63;
  const int j = (wv << 5) | (ln & 31);
  const int h = ln >> 5;
  const int b = blockIdx.x;
  const int base = b * L_SEQ;

  const float* Tq2 = (const float*)(ws + OFF_TQ2);
  const float* Tq3 = (const float*)(ws + OFF_TQ3);
  const float* Tc2 = (const float*)(ws + OFF_TC2);
  const float* Tc3 = (const float*)(ws + OFF_TC3);
  const float* Ts2 = (const float*)(ws + OFF_TSD2);
  const float* Ts3 = (const float*)(ws + OFF_TSD3);
  const float* Ts6 = (const float*)(ws + OFF_TSD6);
  const float* Td2 = (const float*)(ws + OFF_TQD2);
  const float* Td3 = (const float*)(ws + OFF_TQD3);
  const float* Td6 = (const float*)(ws + OFF_TQD6);
  const float* Ta4 = (const float*)(ws + OFF_TA4);
  const float* Ta5 = (const float*)(ws + OFF_TA5);
  const float* Ta6 = (const float*)(ws + OFF_TA6);
  float* Kout = (float*)(ws + OFF_K);

  __shared__ int idxb[5][L_SEQ];
  __shared__ __align__(16) unsigned int kpair[64];
  __shared__ __align__(16) unsigned int sdfp[64];

  idxb[0][tid] = q[base + tid];  idxb[0][tid + 256] = q[base + tid + 256];
  idxb[1][tid] = c[base + tid];  idxb[1][tid + 256] = c[base + tid + 256];
  idxb[2][tid] = sd[base + tid]; idxb[2][tid + 256] = sd[base + tid + 256];
  idxb[3][tid] = qd[base + tid]; idxb[3][tid + 256] = qd[base + tid + 256];
  idxb[4][tid] = a[base + tid];  idxb[4][tid + 256] = a[base + tid + 256];

  // weight half-columns (K rows [64h, 64h+64)) as f16 pairs: 32 regs/matrix
  unsigned int w2h[32], w3h[32], w6h[32], w4h[32], w5h[32];
  const int t0 = h * 64;
#pragma unroll
  for (int p = 0; p < 32; p++) {
    w2h[p] = packh2(W2[(t0 + 2 * p) * 128 + j], W2[(t0 + 2 * p + 1) * 128 + j]);
    w3h[p] = packh2(W3[(t0 + 2 * p) * 128 + j], W3[(t0 + 2 * p + 1) * 128 + j]);
    w6h[p] = packh2(W6[(t0 + 2 * p) * 128 + j], W6[(t0 + 2 * p + 1) * 128 + j]);
    w4h[p] = packh2(W4[(t0 + 2 * p) * 128 + j], W4[(t0 + 2 * p + 1) * 128 + j]);
    w5h[p] = packh2(W5[(t0 + 2 * p) * 128 + j], W5[(t0 + 2 * p + 1) * 128 + j]);
  }

  float k = knowledge[j];
  if (h) ((_Float16*)kpair)[j] = (_Float16)k;
  __syncthreads();

  float gAq2, gAq3, gAc2, gAc3, gAs2, gAs3, gAs6, gAd2, gAd3, gAd6, gAa4, gAa5, gAa6;
  float gBq2, gBq3, gBc2, gBc3, gBs2, gBs3, gBs6, gBd2, gBd3, gBd6, gBa4, gBa5, gBa6;
  PREFETCH(0, gA);
  PREFETCH(1, gB);

#pragma unroll 1
  for (int m = 0; m < L_SEQ / 2; m++) {
    const int l0 = 2 * m;
    const int s2 = (l0 + 2 < L_SEQ) ? (l0 + 2) : (L_SEQ - 1);
    const int s3 = (l0 + 3 < L_SEQ) ? (l0 + 3) : (L_SEQ - 1);
    SCAN_STEP(gA, s2, l0);
    SCAN_STEP(gB, s3, l0 + 1);
  }
}

// ---------------- logits head: one row per thread, Wf broadcast from LDS ----------------
__global__ __launch_bounds__(256, 2) void logits_kernel(
    const float* __restrict__ Wf, const float* __restrict__ bf,
    const char* __restrict__ ws, float* __restrict__ out) {
  __shared__ float WfL[1280];
  __shared__ float bfL[10];
  const int tid = threadIdx.x;
  for (int i = tid; i < 1280; i += 256) WfL[i] = Wf[i];
  if (tid < 10) bfL[tid] = bf[tid];
  __syncthreads();
  const float* K = (const float*)(ws + OFF_K);
  const int nrows = B_SZ * L_SEQ;
  for (int r = blockIdx.x * 256 + tid; r < nrows; r += gridDim.x * 256) {
    const float4* kr = (const float4*)(K + (size_t)r * 128);
    float acc[10];
#pragma unroll
    for (int i = 0; i < 10; i++) acc[i] = bfL[i];
#pragma unroll
    for (int t4 = 0; t4 < 32; t4++) {
      float4 v = kr[t4];
#pragma unroll
      for (int i = 0; i < 10; i++)
        acc[i] += v.x * WfL[(4 * t4 + 0) * 10 + i] + v.y * WfL[(4 * t4 + 1) * 10 + i] +
                  v.z * WfL[(4 * t4 + 2) * 10 + i] + v.w * WfL[(4 * t4 + 3) * 10 + i];
    }
    float* o = out + (size_t)r * 10;
#pragma unroll
    for (int i = 0; i < 10; i++) o[i] = fsig(acc[i]);
  }
}

extern "C" void kernel_launch(void* const* d_in, const int* in_sizes, int n_in,
                              void* d_out, int out_size, void* d_ws, size_t ws_size,
                              hipStream_t stream) {
  const int* q  = (const int*)d_in[0];
  const int* c  = (const int*)d_in[1];
  const int* sd = (const int*)d_in[2];
  const int* qd = (const int*)d_in[3];
  const int* a  = (const int*)d_in[4];
  const float* knowledge = (const float*)d_in[9];
  const float* q_tab  = (const float*)d_in[10];
  const float* c_tab  = (const float*)d_in[11];
  const float* sd_tab = (const float*)d_in[12];
  const float* qd_tab = (const float*)d_in[13];
  const float* a_tab  = (const float*)d_in[14];
  const float* W1 = (const float*)d_in[15];
  const float* b1 = (const float*)d_in[16];
  const float* W2 = (const float*)d_in[17];
  const float* b2 = (const float*)d_in[18];
  const float* W3 = (const float*)d_in[19];
  const float* b3 = (const float*)d_in[20];
  const float* W4 = (const float*)d_in[21];
  const float* b4 = (const float*)d_in[22];
  const float* W5 = (const float*)d_in[23];
  const float* b5 = (const float*)d_in[24];
  const float* W6 = (const float*)d_in[25];
  const float* b6 = (const float*)d_in[26];
  const float* Wf = (const float*)d_in[27];
  const float* bf = (const float*)d_in[28];
  char* ws = (char*)d_ws;
  float* out = (float*)d_out;

  prepA_kernel<<<9, 128, 0, stream>>>(W1, W2, W3, b1, b2, b3, ws);
  gemm_tabs_kernel<2><<<82, 256, 0, stream>>>(q_tab, c_tab, sd_tab, qd_tab, a_tab,
                                              W4, W5, W6, b4, b5, b6, ws);
  gemm_tabs_kernel<3><<<161, 256, 0, stream>>>(q_tab, c_tab, sd_tab, qd_tab, a_tab,
                                               W4, W5, W6, b4, b5, b6, ws);
  scan_kernel<<<B_SZ, 256, 0, stream>>>(q, c, sd, qd, a, knowledge, W2, W3, W4, W5, W6, ws);
  logits_kernel<<<256, 256, 0, stream>>>(Wf, bf, ws, out);
}